// Round 4
// baseline (3899.100 us; speedup 1.0000x reference)
//
#include <hip/hip_runtime.h>
#include <math.h>

typedef __attribute__((ext_vector_type(8))) short short8;
typedef __attribute__((ext_vector_type(4))) float float4v;
typedef __attribute__((ext_vector_type(8))) int int8v;
typedef unsigned short ushort_t;
typedef unsigned char uchar_t;

#define S_LEN 512
#define BATCH 128
#define DMODEL 512
#define HIDDEN 256
#define NTAGS 32
#define MROWS (S_LEN*BATCH)
#define CHUNK 128                 // sequence steps per pre-band
#define EMB_SCALE 22.62741699796952f

__device__ __forceinline__ float bf2f(ushort_t u){
  union { unsigned int i; float f; } v; v.i = ((unsigned int)u)<<16; return v.f;
}
__device__ __forceinline__ ushort_t f2bf(float f){
  union { float f; unsigned int i; } v; v.f = f;
  unsigned int x = v.i;
  x += 0x7fffu + ((x>>16)&1u);
  return (ushort_t)(x>>16);
}
// float -> OCP e4m3fn, RNE, saturate to 448
__device__ __forceinline__ uchar_t f2fp8(float f){
  float a = fabsf(f);
  unsigned int s = (__float_as_uint(f) >> 24) & 0x80u;
  if (a >= 448.f) return (uchar_t)(s | 0x7Eu);
  if (a < 0.015625f){                         // subnormal: m = round(a*512)
    unsigned int q = (unsigned int)__float2int_rn(a * 512.0f);
    return (uchar_t)(s | q);
  }
  unsigned int x = __float_as_uint(a);
  x += 0x7FFFFu + ((x >> 20) & 1u);           // RNE into 3-bit mantissa
  int e = (int)((x >> 23) & 0xFFu) - 127;
  unsigned int m = (x >> 20) & 7u;
  if (e > 8) return (uchar_t)(s | 0x7Eu);
  return (uchar_t)(s | ((unsigned)(e + 7) << 3) | m);
}
__device__ __forceinline__ float sigm(float x){ return 1.0f/(1.0f+__expf(-x)); }
__device__ __forceinline__ float tanh_f(float x){ return 2.0f/(1.0f+__expf(-2.0f*x)) - 1.0f; }

#define MFMA(a,b,c) __builtin_amdgcn_mfma_f32_16x16x32_bf16(a,b,c,0,0,0)
// block-scaled MX fp8 MFMA, K=128, unit scales (e8m0 0x7F = 2^0)
#define MFMAMX(a,b,c) __builtin_amdgcn_mfma_scale_f32_16x16x128_f8f6f4( \
    a, b, c, 0, 0, 0, 0x7F7F7F7F, 0, 0x7F7F7F7F)

// ---------------- elementwise helpers ----------------
__global__ void k_cvt_bf16(const float* __restrict__ s, ushort_t* __restrict__ d, int n){
  int i = blockIdx.x*blockDim.x + threadIdx.x;
  if(i<n) d[i] = f2bf(s[i]);
}
__global__ void k_cvt_fp8(const float* __restrict__ s, uchar_t* __restrict__ d, int n){
  int i = blockIdx.x*blockDim.x + threadIdx.x;
  if(i<n) d[i] = f2fp8(s[i]);
}
__global__ void k_biassum(const float* __restrict__ a, const float* __restrict__ b,
                          float* __restrict__ o, int n){
  int i = blockIdx.x*blockDim.x + threadIdx.x;
  if(i<n) o[i] = a[i]+b[i];
}

// ---------------- embedding: x[s,b,:] = emb[src[s,b],:]*sqrt(D)  (bf16 out) ----
__global__ __launch_bounds__(64) void k_embed(const int* __restrict__ src,
                                              const float* __restrict__ emb,
                                              ushort_t* __restrict__ x){
  int row = blockIdx.x;            // 0..65535  (= s*BATCH+b)
  int t = threadIdx.x;             // 64 threads, 8 elems each
  int tok = src[row];
  const float4v* e = (const float4v*)(emb + (size_t)tok*DMODEL + t*8);
  float4v a = e[0], b = e[1];
  short8 o;
  o[0]=(short)f2bf(a[0]*EMB_SCALE); o[1]=(short)f2bf(a[1]*EMB_SCALE);
  o[2]=(short)f2bf(a[2]*EMB_SCALE); o[3]=(short)f2bf(a[3]*EMB_SCALE);
  o[4]=(short)f2bf(b[0]*EMB_SCALE); o[5]=(short)f2bf(b[1]*EMB_SCALE);
  o[6]=(short)f2bf(b[2]*EMB_SCALE); o[7]=(short)f2bf(b[3]*EMB_SCALE);
  *(short8*)(x + (size_t)row*DMODEL + t*8) = o;
}

// ---------------- band pre-GEMM: C[Mband,N] = A[Mband,512] @ W[N,512]^T + bias -
// perm!=0: write gate-interleaved layout col' = (unit<<2)|gate (unit=col&255,
// gate=col>>8) so the scan kernel reads 4 gates of one unit as one ushort4.
__global__ __launch_bounds__(256) void k_gemm_pre(const ushort_t* __restrict__ A,
                                                  const ushort_t* __restrict__ W,
                                                  const float* __restrict__ bias,
                                                  ushort_t* __restrict__ C, int N,
                                                  int perm){
  __shared__ __align__(16) ushort_t As[64][40];   // +8 pad: 2-way banks only
  __shared__ __align__(16) ushort_t Bs[64][40];
  const int K = 512;
  int bn = blockIdx.x;             // N/64 tiles
  int bm = blockIdx.y;             // Mband/64 tiles
  int tid = threadIdx.x;
  int lane = tid & 63, wave = tid >> 6;
  int wm = wave >> 1, wn = wave & 1;        // 32x32 quadrant per wave
  int srow = tid >> 2, scg = tid & 3;       // staging: row, 8-elem group
  float4v acc[2][2] = {};
  const ushort_t* Ag = A + ((size_t)(bm*64 + srow))*K + scg*8;
  const ushort_t* Wg = W + ((size_t)(bn*64 + srow))*K + scg*8;
  int r = lane & 15;
  int kq = (lane >> 4) * 8;
  for(int kt=0; kt<K/32; ++kt){
    *(short8*)&As[srow][scg*8] = *(const short8*)(Ag + kt*32);
    *(short8*)&Bs[srow][scg*8] = *(const short8*)(Wg + kt*32);
    __syncthreads();
    short8 a0 = *(const short8*)&As[wm*32 +      r][kq];
    short8 a1 = *(const short8*)&As[wm*32 + 16 + r][kq];
    short8 b0 = *(const short8*)&Bs[wn*32 +      r][kq];
    short8 b1 = *(const short8*)&Bs[wn*32 + 16 + r][kq];
    acc[0][0] = MFMA(a0,b0,acc[0][0]);
    acc[0][1] = MFMA(a0,b1,acc[0][1]);
    acc[1][0] = MFMA(a1,b0,acc[1][0]);
    acc[1][1] = MFMA(a1,b1,acc[1][1]);
    __syncthreads();
  }
  int r0 = (lane>>4)*4, cc = lane & 15;
  for(int mt=0;mt<2;++mt) for(int nt=0;nt<2;++nt){
    int col = bn*64 + wn*32 + nt*16 + cc;
    float bv = bias[col];
    int colp = perm ? (((col & 255) << 2) | (col >> 8)) : col;
    for(int j=0;j<4;++j){
      int row = bm*64 + wm*32 + mt*16 + r0 + j;
      C[(size_t)row*N + colp] = f2bf(acc[mt][nt][j] + bv);
    }
  }
}

// ---------------- helpers for the pipelined scan ------------------------------
// h (fp8, 256B in LDS) x Whh-frag -> 8 gate accumulators. A-frag rows 1..15 are
// zeros; only lanes lo==0 read (4 lanes/wave, conflict-free).
__device__ __forceinline__ void mfma_h(const uchar_t* hrow,
                                       const int8v (&wq)[4][2][2],
                                       float4v (&acc)[4][2],
                                       int lo, int hi){
  int8v ha0 = {0,0,0,0,0,0,0,0};
  int8v ha1 = {0,0,0,0,0,0,0,0};
  if(lo==0){
    ha0 = *(const int8v*)(hrow + hi*32);          // k 0..127
    ha1 = *(const int8v*)(hrow + 128 + hi*32);    // k 128..255
  }
  #pragma unroll
  for(int g=0; g<4; ++g){
    acc[g][0] = MFMAMX(ha0, wq[g][0][0], acc[g][0]);
    acc[g][1] = MFMAMX(ha0, wq[g][1][0], acc[g][1]);
    acc[g][0] = MFMAMX(ha1, wq[g][0][1], acc[g][0]);
    acc[g][1] = MFMAMX(ha1, wq[g][1][1], acc[g][1]);
  }
}

// LSTM cell for 32 units (2 uh groups), lanes hi==0 only.
__device__ __forceinline__ void cell_h(const float4v (&acc)[4][2],
                                       const ushort4 (&pc)[2],
                                       float (&c)[2],
                                       uchar_t* hdst,      // this pair's hbuf
                                       ushort_t* xdst,     // xout row + d*HIDDEN
                                       int u0, int lo){
  #pragma unroll
  for(int uh=0; uh<2; ++uh){
    float gi = acc[0][uh][0] + bf2f(pc[uh].x);
    float gf = acc[1][uh][0] + bf2f(pc[uh].y);
    float gg = acc[2][uh][0] + bf2f(pc[uh].z);
    float go = acc[3][uh][0] + bf2f(pc[uh].w);
    float cn = sigm(gf)*c[uh] + sigm(gi)*tanh_f(gg);
    float hn = sigm(go)*tanh_f(cn);
    c[uh] = cn;
    int u = u0 + uh*16 + lo;
    hdst[u] = f2fp8(hn);
    xdst[u] = f2bf(hn);
  }
}

// ---------------- pipelined 2-pair bidirectional LSTM scan --------------------
// grid = 128 blocks x 512 threads: d = bid>>6, batches {b0, b0+64} (same d ->
// weights shared). The two recurrences are time-multiplexed and PHASE-SHIFTED:
//   phase1: MFMA_B(step i)   ∥ cell_A(step i)   -> barrier
//   phase2: MFMA_A(step i+1) ∥ cell_B(step i)   -> barrier
// so one pair's 16 MX MFMAs (matrix pipe) hide the other pair's cell math
// (VALU/trans). Barriers per pair-step unchanged; hbuf is single-buffered per
// pair (every cross-phase read/write hazard is separated by a barrier).
__global__ __launch_bounds__(512,1) void k_scan2p(
    const ushort_t* __restrict__ preF,   // [CHUNK*B][1024] gate-interleaved dir0
    const ushort_t* __restrict__ preB,   // same, dir1 band
    const uchar_t* __restrict__ Wq,      // [2,1024,256] fp8 (this layer)
    uchar_t* __restrict__ hstate,        // [2,128,256] fp8 carry between chunks
    float* __restrict__ cstate,          // [2,128,256] f32
    ushort_t* __restrict__ xout,         // [S*B,512] bf16
    int t0){
  __shared__ __align__(16) uchar_t hbuf[2][288];   // [pair][256B h + pad]
  int bid = blockIdx.x;                  // 0..127
  int d = bid >> 6, b0 = bid & 63;       // batches b0 (pair A), b0+64 (pair B)
  int tid = threadIdx.x;
  int w = tid >> 6, lane = tid & 63;
  int lo = lane & 15, hi = lane >> 4;
  int u0 = w*32;                         // wave's unit base [0,256)

  // initial h for both pairs
  if(tid < 128){
    int pr = tid >> 6, idx = tid & 63;
    int bb = b0 + pr*64;
    *(unsigned int*)&hbuf[pr][idx*4] =
      *(const unsigned int*)(hstate + ((size_t)d*BATCH + bb)*HIDDEN + idx*4);
  }

  // fp8 weights resident: wq[g][uh][kt], 32 B/lane/frag
  int8v wq[4][2][2];
  const uchar_t* Wd = Wq + (size_t)d*1024*HIDDEN;
  #pragma unroll
  for(int g=0; g<4; ++g)
    #pragma unroll
    for(int uh=0; uh<2; ++uh)
      #pragma unroll
      for(int kt=0; kt<2; ++kt)
        wq[g][uh][kt] = *(const int8v*)
          (Wd + (size_t)(g*256 + u0 + uh*16 + lo)*HIDDEN + kt*128 + hi*32);

  float cA[2], cB[2];
  #pragma unroll
  for(int uh=0; uh<2; ++uh){
    cA[uh] = cstate[((size_t)d*BATCH + b0     )*HIDDEN + u0 + uh*16 + lo];
    cB[uh] = cstate[((size_t)d*BATCH + b0 + 64)*HIDDEN + u0 + uh*16 + lo];
  }

  const ushort_t* base = d ? preB : preF;
  const ushort_t* ppA = base + (size_t)b0*1024;
  const ushort_t* ppB = base + (size_t)(b0+64)*1024;
  ushort4 pcA[2], pnA[2], pcB[2], pnB[2];
  {
    int br = d ? (CHUNK-1) : 0;
    if(hi==0){
      #pragma unroll
      for(int uh=0; uh<2; ++uh){
        pcA[uh] = *(const ushort4*)(ppA + (size_t)br*BATCH*1024 + (u0+uh*16+lo)*4);
        pcB[uh] = *(const ushort4*)(ppB + (size_t)br*BATCH*1024 + (u0+uh*16+lo)*4);
      }
    }
  }
  __syncthreads();   // hbuf init visible everywhere

  // prologue: accA <- gates(hA[0])
  float4v accA[4][2] = {};
  mfma_h(&hbuf[0][0], wq, accA, lo, hi);
  // everyone's prologue reads of hbuf[0] must finish before cellA overwrites it
  asm volatile("s_waitcnt lgkmcnt(0)\n\ts_barrier" ::: "memory");

  for(int i=0; i<CHUNK; ++i){
    int i2 = (i+1 < CHUNK) ? i+1 : i;
    int brn = d ? (CHUNK-1-i2) : i2;
    int s = t0 + i;
    int s_eff = d ? (S_LEN-1-s) : s;

    // ---- phase 1: MFMA_B(step i) ∥ cell_A(step i) ----
    if(hi==0){
      #pragma unroll
      for(int uh=0; uh<2; ++uh)
        pnA[uh] = *(const ushort4*)(ppA + (size_t)brn*BATCH*1024 + (u0+uh*16+lo)*4);
    }
    float4v accB[4][2] = {};
    mfma_h(&hbuf[1][0], wq, accB, lo, hi);
    if(hi==0)
      cell_h(accA, pcA, cA, &hbuf[0][0],
             xout + ((size_t)s_eff*BATCH + b0)*DMODEL + d*HIDDEN, u0, lo);
    #pragma unroll
    for(int uh=0; uh<2; ++uh) pcA[uh] = pnA[uh];
    asm volatile("s_waitcnt lgkmcnt(0)\n\ts_barrier" ::: "memory");

    // ---- phase 2: MFMA_A(step i+1) ∥ cell_B(step i) ----
    if(hi==0){
      #pragma unroll
      for(int uh=0; uh<2; ++uh)
        pnB[uh] = *(const ushort4*)(ppB + (size_t)brn*BATCH*1024 + (u0+uh*16+lo)*4);
    }
    #pragma unroll
    for(int g=0; g<4; ++g){
      accA[g][0] = (float4v){0.f,0.f,0.f,0.f};
      accA[g][1] = (float4v){0.f,0.f,0.f,0.f};
    }
    mfma_h(&hbuf[0][0], wq, accA, lo, hi);
    if(hi==0)
      cell_h(accB, pcB, cB, &hbuf[1][0],
             xout + ((size_t)s_eff*BATCH + b0 + 64)*DMODEL + d*HIDDEN, u0, lo);
    #pragma unroll
    for(int uh=0; uh<2; ++uh) pcB[uh] = pnB[uh];
    asm volatile("s_waitcnt lgkmcnt(0)\n\ts_barrier" ::: "memory");
  }

  // write back h and c for both pairs
  if(tid < 128){
    int pr = tid >> 6, idx = tid & 63;
    int bb = b0 + pr*64;
    *(unsigned int*)(hstate + ((size_t)d*BATCH + bb)*HIDDEN + idx*4) =
      *(const unsigned int*)&hbuf[pr][idx*4];
  }
  if(hi==0){
    #pragma unroll
    for(int uh=0; uh<2; ++uh){
      cstate[((size_t)d*BATCH + b0     )*HIDDEN + u0 + uh*16 + lo] = cA[uh];
      cstate[((size_t)d*BATCH + b0 + 64)*HIDDEN + u0 + uh*16 + lo] = cB[uh];
    }
  }
}

// ---------------- logits: [M,32] = x[M,512] @ W_lin^T + b_lin  (f32 out) ------
__global__ __launch_bounds__(128) void k_logits(const ushort_t* __restrict__ x,
                                                const ushort_t* __restrict__ Wl,
                                                const float* __restrict__ bl,
                                                float* __restrict__ logits){
  __shared__ ushort_t xr[16][512];
  __shared__ ushort_t wl[32][520];   // pad -> 4-way max
  int tid = threadIdx.x;
  int base = blockIdx.x * 16;
  for(int i=tid; i<16*64; i+=128){
    int row = i >> 6, cg = i & 63;
    *(short8*)&xr[row][cg*8] = *(const short8*)(x + (size_t)(base+row)*DMODEL + cg*8);
  }
  for(int i=tid; i<32*64; i+=128){
    int row = i >> 6, cg = i & 63;
    *(short8*)&wl[row][cg*8] = *(const short8*)(Wl + (size_t)row*DMODEL + cg*8);
  }
  __syncthreads();
  int rr = tid >> 5, t = tid & 31;
  float bv = bl[t];
  for(int p=0;p<4;++p){
    int row = p*4 + rr;
    float sum = 0.f;
    for(int k8=0;k8<64;++k8){
      short8 xv = *(const short8*)&xr[row][k8*8];
      short8 wv = *(const short8*)&wl[t][k8*8];
      #pragma unroll
      for(int j=0;j<8;++j)
        sum += bf2f((ushort_t)xv[j]) * bf2f((ushort_t)wv[j]);
    }
    logits[((size_t)(base+row))*NTAGS + t] = sum + bv;
  }
}

// ---------------- CRF partition: per-batch alpha recurrence ------------------
// Scaled exp-domain formulation: a[t] = exp(alpha[t] - M).  Per step:
//   a_new[t] = (sum_j a[j]*expT[j][t]) * exp(e[t])
// expT held in 32 VGPRs/lane (computed once); only ONE transcendental per
// step on the critical path, and its input (emission) is prefetched 2 steps
// ahead.  All sums are of positive terms (no cancellation).  Exact power-of-2
// rescale keeps a in range; triggered by a cheap wave-uniform __any/__all
// check.  Lanes 32-63 mirror lanes 0-31 (uniform wave ops, no divergence).
__global__ __launch_bounds__(64) void k_crf(const float* __restrict__ logits,
                                            const float* __restrict__ trans,
                                            float* __restrict__ logz){
  __shared__ __align__(16) float sh[32];
  int b = blockIdx.x, tid = threadIdx.x;
  int t = tid & 31;                       // lanes 32-63 mirror 0-31

  // per-lane column of exp(T): eT[j] = exp(trans[j][t])
  float eT[32];
  #pragma unroll
  for(int j=0;j<32;++j) eT[j] = __expf(trans[j*NTAGS + t]);

  // init: alpha0 = logits[0,b,:]; a = exp(alpha0 - m0), M = m0
  float al0 = logits[(size_t)b*NTAGS + t];
  float m0 = al0;
  #pragma unroll
  for(int o=1;o<32;o<<=1) m0 = fmaxf(m0, __shfl_xor(m0, o));
  float Mf = m0;
  float a = __expf(al0 - m0);

  const size_t stp = (size_t)BATCH*NTAGS;
  const float* ebase = logits + (size_t)b*NTAGS + t;
  float eCur = ebase[stp*1];              // emission for step 1
  float eNxt = ebase[stp*2];              // emission for step 2
  const float* eptr = ebase + stp*3;      // prefetch pointer (step i+2 at i=1)

  for(int i=1;i<S_LEN;++i){
    float expE = __expf(eCur);            // input was prefetched 2 steps ago
    if(tid < 32) sh[t] = a;
    __syncthreads();
    // prefetch emission for step i+2 (independent of recurrence)
    float eP = 0.f;
    if(i+2 < S_LEN) eP = *eptr;
    eptr += stp;
    // s_t = sum_j a[j] * expT[j][t] — 4 independent FMA chains
    float s0=0.f, s1=0.f, s2=0.f, s3=0.f;
    const float4v* s4 = (const float4v*)sh;
    #pragma unroll
    for(int q=0;q<8;++q){
      float4v v = s4[q];
      s0 = __fmaf_rn(v[0], eT[q*4+0], s0);
      s1 = __fmaf_rn(v[1], eT[q*4+1], s1);
      s2 = __fmaf_rn(v[2], eT[q*4+2], s2);
      s3 = __fmaf_rn(v[3], eT[q*4+3], s3);
    }
    a = ((s0+s1)+(s2+s3)) * expE;
    eCur = eNxt; eNxt = eP;
    // exact power-of-2 renorm when out of range (wave-uniform branch)
    if(__any(a > 1.1529215e18f) || __all(a < 9.0949470e-13f)){   // 2^60 / 2^-40
      float m = a;
      #pragma unroll
      for(int o=1;o<32;o<<=1) m = fmaxf(m, __shfl_xor(m, o));
      int e2 = (int)((__float_as_uint(m)>>23)&255u) - 127;
      float scl = __uint_as_float((unsigned)(127 - e2) << 23);   // 2^-e2 exact
      a *= scl;
      Mf += (float)e2 * 0.69314718055994531f;
    }
    __syncthreads();
  }
  // logz = M + log(sum_t a)
  float sum = a;
  #pragma unroll
  for(int o=1;o<32;o<<=1) sum += __shfl_xor(sum, o);
  if(tid==0) logz[b] = Mf + __logf(sum);
}

// ---------------- gold path score + combine ----------------------------------
__global__ __launch_bounds__(256) void k_gold(const float* __restrict__ logits,
                                              const int* __restrict__ tgt,
                                              const float* __restrict__ trans,
                                              const float* __restrict__ logz,
                                              float* __restrict__ partial){
  int b = blockIdx.x, tid = threadIdx.x;
  float local = 0.f;
  for(int s=tid; s<S_LEN; s+=256){
    int ts = tgt[s*BATCH + b];
    local += logits[((size_t)s*BATCH + b)*NTAGS + ts];
    if(s > 0){
      int tp = tgt[(s-1)*BATCH + b];
      local += trans[tp*NTAGS + ts];
    }
  }
  __shared__ float red[4];
  for(int o=32;o>0;o>>=1) local += __shfl_down(local, o, 64);
  if((tid&63)==0) red[tid>>6] = local;
  __syncthreads();
  if(tid==0) partial[b] = logz[b] - (red[0]+red[1]+red[2]+red[3]);
}
__global__ __launch_bounds__(128) void k_final(const float* __restrict__ partial,
                                               float* __restrict__ out){
  int t = threadIdx.x;
  float v = partial[t];
  for(int o=32;o>0;o>>=1) v += __shfl_down(v, o, 64);
  __shared__ float r2[2];
  if((t&63)==0) r2[t>>6] = v;
  __syncthreads();
  if(t==0) out[0] = (r2[0]+r2[1]) * (1.0f/BATCH);
}

// ---------------- launcher ---------------------------------------------------
extern "C" void kernel_launch(void* const* d_in, const int* in_sizes, int n_in,
                              void* d_out, int out_size, void* d_ws, size_t ws_size,
                              hipStream_t stream){
  const int*   src   = (const int*)d_in[0];
  const int*   tgt   = (const int*)d_in[1];
  const float* emb   = (const float*)d_in[2];
  const float* Wih   = (const float*)d_in[3];
  const float* Whh   = (const float*)d_in[4];
  const float* bih   = (const float*)d_in[5];
  const float* bhh   = (const float*)d_in[6];
  const float* Wlin  = (const float*)d_in[7];
  const float* blin  = (const float*)d_in[8];
  const float* trans = (const float*)d_in[9];
  float* out = (float*)d_out;
  char* ws = (char*)d_ws;

  // workspace layout — total ~197.4 MB
  ushort_t* xA     = (ushort_t*)(ws + 0);              //  67,108,864
  ushort_t* xB     = (ushort_t*)(ws + 67108864);       //  67,108,864
  ushort_t* preF   = (ushort_t*)(ws + 134217728);      //  33,554,432 [CHUNK*B,1024]
  ushort_t* preB   = (ushort_t*)(ws + 167772160);      //  33,554,432
  ushort_t* WihB   = (ushort_t*)(ws + 201326592);      //   4,194,304
  uchar_t*  Wq8    = (uchar_t*) (ws + 205520896);      //   1,048,576 fp8 Whh
  ushort_t* WlinB  = (ushort_t*)(ws + 206569472);      //      32,768
  float*    bsum   = (float*)   (ws + 206602240);      //      16,384
  uchar_t*  hstate = (uchar_t*) (ws + 206618624);      //      65,536 fp8
  float*    cstate = (float*)   (ws + 206684160);      //     262,144
  float*    logz   = (float*)   (ws + 206946304);      //         512
  float*    partial= (float*)   (ws + 206946816);      //         512
  float*    logits = (float*)   (ws + 134217728);      // aliases preF (dead by then)

  // weight conversions
  k_cvt_bf16<<<dim3(8192),dim3(256),0,stream>>>(Wih,  WihB,  2*2*1024*512);
  k_cvt_fp8 <<<dim3(4096),dim3(256),0,stream>>>(Whh,  Wq8,   2*2*1024*256);
  k_cvt_bf16<<<dim3(64),  dim3(256),0,stream>>>(Wlin, WlinB, 32*512);
  k_biassum <<<dim3(16),  dim3(256),0,stream>>>(bih, bhh, bsum, 2*2*1024);

  // embedding
  k_embed<<<dim3(MROWS),dim3(64),0,stream>>>(src, emb, xA);

  for(int l=0;l<2;++l){
    const ushort_t* xin = l ? xB : xA;
    ushort_t*      xout = l ? xA : xB;
    // zero h (fp8) + c (f32) — contiguous
    hipMemsetAsync(hstate, 0, 65536 + 262144, stream);
    const uchar_t* WqL = Wq8 + (size_t)l*2*1024*HIDDEN;
    for(int cI=0;cI<S_LEN/CHUNK;++cI){
      int t0 = cI*CHUNK;
      // dir0 band: sequence rows [t0, t0+CHUNK)
      k_gemm_pre<<<dim3(16, CHUNK*BATCH/64),dim3(256),0,stream>>>(
          xin + (size_t)t0*BATCH*DMODEL,
          WihB + (size_t)(l*2+0)*1024*DMODEL,
          bsum + (l*2+0)*1024, preF, 1024, 1);
      // dir1 band: sequence rows [S-t0-CHUNK, S-t0)
      k_gemm_pre<<<dim3(16, CHUNK*BATCH/64),dim3(256),0,stream>>>(
          xin + (size_t)(S_LEN - t0 - CHUNK)*BATCH*DMODEL,
          WihB + (size_t)(l*2+1)*1024*DMODEL,
          bsum + (l*2+1)*1024, preB, 1024, 1);
      // pipelined 2-pair scan: 128 blocks, 2 batches per block (same dir)
      k_scan2p<<<dim3(128),dim3(512),0,stream>>>(
          preF, preB, WqL, hstate, cstate, xout, t0);
    }
  }

  k_logits<<<dim3(MROWS/16),dim3(128),0,stream>>>(xA, WlinB, blin, logits);
  k_crf   <<<dim3(BATCH),dim3(64),0,stream>>>(logits, trans, logz);
  k_gold  <<<dim3(BATCH),dim3(256),0,stream>>>(logits, tgt, trans, logz, partial);
  k_final <<<dim3(1),dim3(128),0,stream>>>(partial, out);
}

// Round 5
// 3165.373 us; speedup vs baseline: 1.2318x; 1.2318x over previous
//
#include <hip/hip_runtime.h>
#include <math.h>

typedef __attribute__((ext_vector_type(8))) short short8;
typedef __attribute__((ext_vector_type(4))) float float4v;
typedef __attribute__((ext_vector_type(8))) int int8v;
typedef unsigned short ushort_t;
typedef unsigned char uchar_t;

#define S_LEN 512
#define BATCH 128
#define DMODEL 512
#define HIDDEN 256
#define NTAGS 32
#define MROWS (S_LEN*BATCH)
#define CHUNK 64                  // sequence steps per pre-band (double-buffered)
#define NCH (S_LEN/CHUNK)         // 8 chunks
#define EMB_SCALE 22.62741699796952f

__device__ __forceinline__ float bf2f(ushort_t u){
  union { unsigned int i; float f; } v; v.i = ((unsigned int)u)<<16; return v.f;
}
__device__ __forceinline__ ushort_t f2bf(float f){
  union { float f; unsigned int i; } v; v.f = f;
  unsigned int x = v.i;
  x += 0x7fffu + ((x>>16)&1u);
  return (ushort_t)(x>>16);
}
// float -> OCP e4m3fn, RNE, saturate to 448
__device__ __forceinline__ uchar_t f2fp8(float f){
  float a = fabsf(f);
  unsigned int s = (__float_as_uint(f) >> 24) & 0x80u;
  if (a >= 448.f) return (uchar_t)(s | 0x7Eu);
  if (a < 0.015625f){                         // subnormal: m = round(a*512)
    unsigned int q = (unsigned int)__float2int_rn(a * 512.0f);
    return (uchar_t)(s | q);
  }
  unsigned int x = __float_as_uint(a);
  x += 0x7FFFFu + ((x >> 20) & 1u);           // RNE into 3-bit mantissa
  int e = (int)((x >> 23) & 0xFFu) - 127;
  unsigned int m = (x >> 20) & 7u;
  if (e > 8) return (uchar_t)(s | 0x7Eu);
  return (uchar_t)(s | ((unsigned)(e + 7) << 3) | m);
}
__device__ __forceinline__ float sigm(float x){ return 1.0f/(1.0f+__expf(-x)); }
__device__ __forceinline__ float tanh_f(float x){ return 2.0f/(1.0f+__expf(-2.0f*x)) - 1.0f; }

#define MFMA(a,b,c) __builtin_amdgcn_mfma_f32_16x16x32_bf16(a,b,c,0,0,0)
// block-scaled MX fp8 MFMA, K=128, unit scales (e8m0 0x7F = 2^0)
#define MFMAMX(a,b,c) __builtin_amdgcn_mfma_scale_f32_16x16x128_f8f6f4( \
    a, b, c, 0, 0, 0, 0x7F7F7F7F, 0, 0x7F7F7F7F)

// ---------------- elementwise helpers ----------------
__global__ void k_cvt_bf16(const float* __restrict__ s, ushort_t* __restrict__ d, int n){
  int i = blockIdx.x*blockDim.x + threadIdx.x;
  if(i<n) d[i] = f2bf(s[i]);
}
__global__ void k_cvt_fp8(const float* __restrict__ s, uchar_t* __restrict__ d, int n){
  int i = blockIdx.x*blockDim.x + threadIdx.x;
  if(i<n) d[i] = f2fp8(s[i]);
}
__global__ void k_biassum(const float* __restrict__ a, const float* __restrict__ b,
                          float* __restrict__ o, int n){
  int i = blockIdx.x*blockDim.x + threadIdx.x;
  if(i<n) o[i] = a[i]+b[i];
}

// ---------------- embedding: x[s,b,:] = emb[src[s,b],:]*sqrt(D)  (bf16 out) ----
__global__ __launch_bounds__(64) void k_embed(const int* __restrict__ src,
                                              const float* __restrict__ emb,
                                              ushort_t* __restrict__ x){
  int row = blockIdx.x;            // 0..65535  (= s*BATCH+b)
  int t = threadIdx.x;             // 64 threads, 8 elems each
  int tok = src[row];
  const float4v* e = (const float4v*)(emb + (size_t)tok*DMODEL + t*8);
  float4v a = e[0], b = e[1];
  short8 o;
  o[0]=(short)f2bf(a[0]*EMB_SCALE); o[1]=(short)f2bf(a[1]*EMB_SCALE);
  o[2]=(short)f2bf(a[2]*EMB_SCALE); o[3]=(short)f2bf(a[3]*EMB_SCALE);
  o[4]=(short)f2bf(b[0]*EMB_SCALE); o[5]=(short)f2bf(b[1]*EMB_SCALE);
  o[6]=(short)f2bf(b[2]*EMB_SCALE); o[7]=(short)f2bf(b[3]*EMB_SCALE);
  *(short8*)(x + (size_t)row*DMODEL + t*8) = o;
}

// ---------------- 64x64 GEMM tile body (256-thread unit) ----------------------
// C[Mband,1024] = A[Mband,512] @ W[1024,512]^T + bias, gate-interleaved perm.
// Called by k_gemm_pre (standalone, 256 thr) and k_fused (2 units x 256 thr;
// __syncthreads spans 512 thr but both units run identical trip counts).
__device__ __forceinline__ void gemm_tile(const ushort_t* __restrict__ A,
                                          const ushort_t* __restrict__ W,
                                          const float* __restrict__ bias,
                                          ushort_t* __restrict__ C,
                                          int bm, int bn, int t,
                                          ushort_t (*As)[40], ushort_t (*Bs)[40]){
  const int K = 512;
  int lane = t & 63, wave = t >> 6;
  int wm = wave >> 1, wn = wave & 1;        // 32x32 quadrant per wave
  int srow = t >> 2, scg = t & 3;           // staging: row, 8-elem group
  float4v acc[2][2] = {};
  const ushort_t* Ag = A + ((size_t)(bm*64 + srow))*K + scg*8;
  const ushort_t* Wg = W + ((size_t)(bn*64 + srow))*K + scg*8;
  int r = lane & 15;
  int kq = (lane >> 4) * 8;
  for(int kt=0; kt<K/32; ++kt){
    *(short8*)&As[srow][scg*8] = *(const short8*)(Ag + kt*32);
    *(short8*)&Bs[srow][scg*8] = *(const short8*)(Wg + kt*32);
    __syncthreads();
    short8 a0 = *(const short8*)&As[wm*32 +      r][kq];
    short8 a1 = *(const short8*)&As[wm*32 + 16 + r][kq];
    short8 b0 = *(const short8*)&Bs[wn*32 +      r][kq];
    short8 b1 = *(const short8*)&Bs[wn*32 + 16 + r][kq];
    acc[0][0] = MFMA(a0,b0,acc[0][0]);
    acc[0][1] = MFMA(a0,b1,acc[0][1]);
    acc[1][0] = MFMA(a1,b0,acc[1][0]);
    acc[1][1] = MFMA(a1,b1,acc[1][1]);
    __syncthreads();
  }
  int r0 = (lane>>4)*4, cc = lane & 15;
  for(int mt=0;mt<2;++mt) for(int nt=0;nt<2;++nt){
    int col = bn*64 + wn*32 + nt*16 + cc;
    float bv = bias[col];
    int colp = ((col & 255) << 2) | (col >> 8);   // gate-interleave
    for(int j=0;j<4;++j){
      int row = bm*64 + wm*32 + mt*16 + r0 + j;
      C[(size_t)row*1024 + colp] = f2bf(acc[mt][nt][j] + bv);
    }
  }
}

// standalone pre-GEMM (layer prologue, chunk 0)
__global__ __launch_bounds__(256) void k_gemm_pre(const ushort_t* __restrict__ A,
                                                  const ushort_t* __restrict__ W,
                                                  const float* __restrict__ bias,
                                                  ushort_t* __restrict__ C){
  __shared__ __align__(16) ushort_t As[64][40];
  __shared__ __align__(16) ushort_t Bs[64][40];
  gemm_tile(A, W, bias, C, blockIdx.y, blockIdx.x, threadIdx.x, As, Bs);
}

// ---------------- fused scan(chunk c) + pre-GEMM(chunk c+1) -------------------
// 256 blocks x 512 thr, 96KB LDS forces exactly 1 block/CU (no scan/GEMM CU
// sharing). Blocks 0..127: scan, d = bid>>6, batches {b0, b0+64} PACKED INTO
// MFMA A-ROWS 0/1 (lanes lo==0 carry h_A, lo==1 carry h_B; outputs in acc regs
// 0/1 of lanes hi==0) -- same 16 MFMAs/wave/step serve both recurrences.
// Blocks 128..255: 2x 256-thr GEMM units each, 16 tiles/unit, next chunk's
// pre-band (both dirs) into the other band parity.
__global__ __launch_bounds__(512,1) void k_fused(
    const ushort_t* __restrict__ preF,   // scan: [CHUNK*B][1024] dir0 band (chunk c)
    const ushort_t* __restrict__ preB,   // scan: dir1 band
    const uchar_t* __restrict__ Wq,      // [2,1024,256] fp8 Whh (this layer)
    uchar_t* __restrict__ hstate,        // [2,128,256] fp8
    float* __restrict__ cstate,          // [2,128,256] f32
    ushort_t* __restrict__ xout,         // [S*B,512] bf16
    int t0,
    const ushort_t* __restrict__ xin,    // gemm: layer input
    const ushort_t* __restrict__ WihL,   // gemm: [2,1024,512] bf16 (this layer)
    const float* __restrict__ bsumL,     // gemm: [2,1024]
    ushort_t* __restrict__ outF,         // gemm: band chunk c+1 dir0
    ushort_t* __restrict__ outB,         // gemm: band chunk c+1 dir1
    int t0n, int ngem){
  __shared__ __align__(16) uchar_t smem[98304];   // >80KB -> 1 block/CU
  int bid = blockIdx.x;
  int tid = threadIdx.x;

  if(bid < 128){
    // ================= scan path =================
    int d = bid >> 6, b0 = bid & 63;     // batches b0 (rows 0), b0+64 (rows 1)
    int w = tid >> 6, lane = tid & 63;
    int lo = lane & 15, hi = lane >> 4;
    int u0 = w*32;                       // wave's unit base [0,256)
    // hbuf: hA[p] @ p*512, hB[p] @ 2048+p*512 (256B each, double-buffered)
    if(tid < 64)
      *(unsigned int*)&smem[tid*4] =
        *(const unsigned int*)(hstate + ((size_t)d*BATCH + b0)*HIDDEN + tid*4);
    else if(tid < 128){
      int idx = tid - 64;
      *(unsigned int*)&smem[2048 + idx*4] =
        *(const unsigned int*)(hstate + ((size_t)d*BATCH + b0+64)*HIDDEN + idx*4);
    }

    // fp8 weights resident: wq[g][uh][kt], 32 B/lane/frag (B-frag col = lo)
    int8v wq[4][2][2];
    const uchar_t* Wd = Wq + (size_t)d*1024*HIDDEN;
    #pragma unroll
    for(int g=0; g<4; ++g)
      #pragma unroll
      for(int uh=0; uh<2; ++uh)
        #pragma unroll
        for(int kt=0; kt<2; ++kt)
          wq[g][uh][kt] = *(const int8v*)
            (Wd + (size_t)(g*256 + u0 + uh*16 + lo)*HIDDEN + kt*128 + hi*32);

    float cA[2], cB[2];
    #pragma unroll
    for(int uh=0; uh<2; ++uh){
      cA[uh] = cstate[((size_t)d*BATCH + b0     )*HIDDEN + u0 + uh*16 + lo];
      cB[uh] = cstate[((size_t)d*BATCH + b0 + 64)*HIDDEN + u0 + uh*16 + lo];
    }

    const ushort_t* base = d ? preB : preF;
    const ushort_t* ppA = base + (size_t)b0*1024;
    const ushort_t* ppB = base + (size_t)(b0+64)*1024;
    ushort4 pcA[2], pcB[2], pnA[2], pnB[2];
    {
      int br = d ? (CHUNK-1) : 0;
      if(hi==0){
        #pragma unroll
        for(int uh=0; uh<2; ++uh){
          pcA[uh] = *(const ushort4*)(ppA + (size_t)br*BATCH*1024 + (u0+uh*16+lo)*4);
          pcB[uh] = *(const ushort4*)(ppB + (size_t)br*BATCH*1024 + (u0+uh*16+lo)*4);
        }
      }
    }
    __syncthreads();

    for(int sb=0; sb<CHUNK; ++sb){
      int p = sb & 1;
      uchar_t* hAc = smem + p*512;
      uchar_t* hBc = smem + 2048 + p*512;
      uchar_t* hAn = smem + (p^1)*512;
      uchar_t* hBn = smem + 2048 + (p^1)*512;
      // prefetch next step's pre (flies across the barrier)
      int sb2 = (sb+1 < CHUNK) ? sb+1 : sb;
      int br2 = d ? (CHUNK-1-sb2) : sb2;
      if(hi==0){
        #pragma unroll
        for(int uh=0; uh<2; ++uh){
          pnA[uh] = *(const ushort4*)(ppA + (size_t)br2*BATCH*1024 + (u0+uh*16+lo)*4);
          pnB[uh] = *(const ushort4*)(ppB + (size_t)br2*BATCH*1024 + (u0+uh*16+lo)*4);
        }
      }

      // A-frag: row 0 (lanes lo==0) = h_A, row 1 (lanes lo==1) = h_B, rest 0
      int8v ha0 = {0,0,0,0,0,0,0,0};
      int8v ha1 = {0,0,0,0,0,0,0,0};
      if(lo==0){
        ha0 = *(const int8v*)(hAc + hi*32);          // k 0..127
        ha1 = *(const int8v*)(hAc + 128 + hi*32);    // k 128..255
      } else if(lo==1){
        ha0 = *(const int8v*)(hBc + hi*32);
        ha1 = *(const int8v*)(hBc + 128 + hi*32);
      }
      float4v acc[4][2] = {};
      #pragma unroll
      for(int g=0; g<4; ++g){
        acc[g][0] = MFMAMX(ha0, wq[g][0][0], acc[g][0]);
        acc[g][1] = MFMAMX(ha0, wq[g][1][0], acc[g][1]);
        acc[g][0] = MFMAMX(ha1, wq[g][0][1], acc[g][0]);
        acc[g][1] = MFMAMX(ha1, wq[g][1][1], acc[g][1]);
      }

      int s = t0 + sb;
      int s_eff = d ? (S_LEN-1-s) : s;
      if(hi==0){
        ushort_t* xoA = xout + ((size_t)s_eff*BATCH + b0     )*DMODEL + d*HIDDEN;
        ushort_t* xoB = xout + ((size_t)s_eff*BATCH + b0 + 64)*DMODEL + d*HIDDEN;
        #pragma unroll
        for(int uh=0; uh<2; ++uh){
          // batch A from acc reg 0 (M-row 0)
          float giA = acc[0][uh][0] + bf2f(pcA[uh].x);
          float gfA = acc[1][uh][0] + bf2f(pcA[uh].y);
          float ggA = acc[2][uh][0] + bf2f(pcA[uh].z);
          float goA = acc[3][uh][0] + bf2f(pcA[uh].w);
          float cnA = sigm(gfA)*cA[uh] + sigm(giA)*tanh_f(ggA);
          float hnA = sigm(goA)*tanh_f(cnA);
          cA[uh] = cnA;
          // batch B from acc reg 1 (M-row 1)
          float giB = acc[0][uh][1] + bf2f(pcB[uh].x);
          float gfB = acc[1][uh][1] + bf2f(pcB[uh].y);
          float ggB = acc[2][uh][1] + bf2f(pcB[uh].z);
          float goB = acc[3][uh][1] + bf2f(pcB[uh].w);
          float cnB = sigm(gfB)*cB[uh] + sigm(giB)*tanh_f(ggB);
          float hnB = sigm(goB)*tanh_f(cnB);
          cB[uh] = cnB;
          int u = u0 + uh*16 + lo;
          hAn[u] = f2fp8(hnA);
          hBn[u] = f2fp8(hnB);
          xoA[u] = f2bf(hnA);
          xoB[u] = f2bf(hnB);
        }
      }
      // raw barrier: order LDS only; vmem (prefetch + xout stores) in flight
      asm volatile("s_waitcnt lgkmcnt(0)\n\ts_barrier" ::: "memory");
      #pragma unroll
      for(int uh=0; uh<2; ++uh){ pcA[uh] = pnA[uh]; pcB[uh] = pnB[uh]; }
    }

    // write back h (CHUNK even -> final h in p=0 buffers) and c
    if(tid < 64)
      *(unsigned int*)(hstate + ((size_t)d*BATCH + b0)*HIDDEN + tid*4) =
        *(const unsigned int*)&smem[tid*4];
    else if(tid < 128){
      int idx = tid - 64;
      *(unsigned int*)(hstate + ((size_t)d*BATCH + b0+64)*HIDDEN + idx*4) =
        *(const unsigned int*)&smem[2048 + idx*4];
    }
    if(hi==0){
      #pragma unroll
      for(int uh=0; uh<2; ++uh){
        cstate[((size_t)d*BATCH + b0     )*HIDDEN + u0 + uh*16 + lo] = cA[uh];
        cstate[((size_t)d*BATCH + b0 + 64)*HIDDEN + u0 + uh*16 + lo] = cB[uh];
      }
    }
  } else if(ngem){
    // ================= GEMM path: pre-band for chunk c+1 =================
    int half = tid >> 8;                 // 2 units of 256 thr
    int tu = tid & 255;
    int unit = (bid - 128)*2 + half;     // 0..255
    ushort_t (*As)[40] = (ushort_t(*)[40])(smem + half*10240);
    ushort_t (*Bs)[40] = (ushort_t(*)[40])(smem + half*10240 + 5120);
    #pragma unroll 1
    for(int it=0; it<16; ++it){
      int tIdx = unit + 256*it;          // 0..4095
      int dd  = tIdx >> 11;              // 2048 tiles per dir
      int rem = tIdx & 2047;
      int bm = rem >> 4, bn = rem & 15;
      const ushort_t* A = xin +
        (size_t)(dd ? (S_LEN - t0n - CHUNK) : t0n)*BATCH*DMODEL;
      const ushort_t* W = WihL + (size_t)dd*1024*DMODEL;
      const float* bias = bsumL + dd*1024;
      ushort_t* C = dd ? outB : outF;
      gemm_tile(A, W, bias, C, bm, bn, tu, As, Bs);
    }
  }
}

// ---------------- logits: [M,32] = x[M,512] @ W_lin^T + b_lin  (f32 out) ------
__global__ __launch_bounds__(128) void k_logits(const ushort_t* __restrict__ x,
                                                const ushort_t* __restrict__ Wl,
                                                const float* __restrict__ bl,
                                                float* __restrict__ logits){
  __shared__ ushort_t xr[16][512];
  __shared__ ushort_t wl[32][520];   // pad -> 4-way max
  int tid = threadIdx.x;
  int base = blockIdx.x * 16;
  for(int i=tid; i<16*64; i+=128){
    int row = i >> 6, cg = i & 63;
    *(short8*)&xr[row][cg*8] = *(const short8*)(x + (size_t)(base+row)*DMODEL + cg*8);
  }
  for(int i=tid; i<32*64; i+=128){
    int row = i >> 6, cg = i & 63;
    *(short8*)&wl[row][cg*8] = *(const short8*)(Wl + (size_t)row*DMODEL + cg*8);
  }
  __syncthreads();
  int rr = tid >> 5, t = tid & 31;
  float bv = bl[t];
  for(int p=0;p<4;++p){
    int row = p*4 + rr;
    float sum = 0.f;
    for(int k8=0;k8<64;++k8){
      short8 xv = *(const short8*)&xr[row][k8*8];
      short8 wv = *(const short8*)&wl[t][k8*8];
      #pragma unroll
      for(int j=0;j<8;++j)
        sum += bf2f((ushort_t)xv[j]) * bf2f((ushort_t)wv[j]);
    }
    logits[((size_t)(base+row))*NTAGS + t] = sum + bv;
  }
}

// ---------------- CRF partition: per-batch alpha recurrence ------------------
// Scaled exp-domain: a[t]=exp(alpha[t]-M); a_new = (sum_j a[j]*expT[j][t])*exp(e).
// One transcendental/step on the critical path (emission prefetched 2 ahead);
// exact power-of-2 renorm on wave-uniform trigger.
__global__ __launch_bounds__(64) void k_crf(const float* __restrict__ logits,
                                            const float* __restrict__ trans,
                                            float* __restrict__ logz){
  __shared__ __align__(16) float sh[32];
  int b = blockIdx.x, tid = threadIdx.x;
  int t = tid & 31;                       // lanes 32-63 mirror 0-31

  float eT[32];
  #pragma unroll
  for(int j=0;j<32;++j) eT[j] = __expf(trans[j*NTAGS + t]);

  float al0 = logits[(size_t)b*NTAGS + t];
  float m0 = al0;
  #pragma unroll
  for(int o=1;o<32;o<<=1) m0 = fmaxf(m0, __shfl_xor(m0, o));
  float Mf = m0;
  float a = __expf(al0 - m0);

  const size_t stp = (size_t)BATCH*NTAGS;
  const float* ebase = logits + (size_t)b*NTAGS + t;
  float eCur = ebase[stp*1];
  float eNxt = ebase[stp*2];
  const float* eptr = ebase + stp*3;

  for(int i=1;i<S_LEN;++i){
    float expE = __expf(eCur);
    if(tid < 32) sh[t] = a;
    __syncthreads();
    float eP = 0.f;
    if(i+2 < S_LEN) eP = *eptr;
    eptr += stp;
    float s0=0.f, s1=0.f, s2=0.f, s3=0.f;
    const float4v* s4 = (const float4v*)sh;
    #pragma unroll
    for(int q=0;q<8;++q){
      float4v v = s4[q];
      s0 = __fmaf_rn(v[0], eT[q*4+0], s0);
      s1 = __fmaf_rn(v[1], eT[q*4+1], s1);
      s2 = __fmaf_rn(v[2], eT[q*4+2], s2);
      s3 = __fmaf_rn(v[3], eT[q*4+3], s3);
    }
    a = ((s0+s1)+(s2+s3)) * expE;
    eCur = eNxt; eNxt = eP;
    if(__any(a > 1.1529215e18f) || __all(a < 9.0949470e-13f)){   // 2^60 / 2^-40
      float m = a;
      #pragma unroll
      for(int o=1;o<32;o<<=1) m = fmaxf(m, __shfl_xor(m, o));
      int e2 = (int)((__float_as_uint(m)>>23)&255u) - 127;
      float scl = __uint_as_float((unsigned)(127 - e2) << 23);
      a *= scl;
      Mf += (float)e2 * 0.69314718055994531f;
    }
    __syncthreads();
  }
  float sum = a;
  #pragma unroll
  for(int o=1;o<32;o<<=1) sum += __shfl_xor(sum, o);
  if(tid==0) logz[b] = Mf + __logf(sum);
}

// ---------------- gold path score + combine ----------------------------------
__global__ __launch_bounds__(256) void k_gold(const float* __restrict__ logits,
                                              const int* __restrict__ tgt,
                                              const float* __restrict__ trans,
                                              const float* __restrict__ logz,
                                              float* __restrict__ partial){
  int b = blockIdx.x, tid = threadIdx.x;
  float local = 0.f;
  for(int s=tid; s<S_LEN; s+=256){
    int ts = tgt[s*BATCH + b];
    local += logits[((size_t)s*BATCH + b)*NTAGS + ts];
    if(s > 0){
      int tp = tgt[(s-1)*BATCH + b];
      local += trans[tp*NTAGS + ts];
    }
  }
  __shared__ float red[4];
  for(int o=32;o>0;o>>=1) local += __shfl_down(local, o, 64);
  if((tid&63)==0) red[tid>>6] = local;
  __syncthreads();
  if(tid==0) partial[b] = logz[b] - (red[0]+red[1]+red[2]+red[3]);
}
__global__ __launch_bounds__(128) void k_final(const float* __restrict__ partial,
                                               float* __restrict__ out){
  int t = threadIdx.x;
  float v = partial[t];
  for(int o=32;o>0;o>>=1) v += __shfl_down(v, o, 64);
  __shared__ float r2[2];
  if((t&63)==0) r2[t>>6] = v;
  __syncthreads();
  if(t==0) out[0] = (r2[0]+r2[1]) * (1.0f/BATCH);
}

// ---------------- launcher ---------------------------------------------------
extern "C" void kernel_launch(void* const* d_in, const int* in_sizes, int n_in,
                              void* d_out, int out_size, void* d_ws, size_t ws_size,
                              hipStream_t stream){
  const int*   src   = (const int*)d_in[0];
  const int*   tgt   = (const int*)d_in[1];
  const float* emb   = (const float*)d_in[2];
  const float* Wih   = (const float*)d_in[3];
  const float* Whh   = (const float*)d_in[4];
  const float* bih   = (const float*)d_in[5];
  const float* bhh   = (const float*)d_in[6];
  const float* Wlin  = (const float*)d_in[7];
  const float* blin  = (const float*)d_in[8];
  const float* trans = (const float*)d_in[9];
  float* out = (float*)d_out;
  char* ws = (char*)d_ws;

  // workspace layout — total ~197.4 MB (unchanged footprint)
  const size_t BSZ = (size_t)CHUNK*BATCH*1024*sizeof(ushort_t);   // 16 MB/band
  ushort_t* xA     = (ushort_t*)(ws + 0);              //  67,108,864
  ushort_t* xB     = (ushort_t*)(ws + 67108864);       //  67,108,864
  char*     bands  =             ws + 134217728;       //  4 x 16 MB (F0,B0,F1,B1)
  ushort_t* bF[2]  = { (ushort_t*)(bands),           (ushort_t*)(bands + 2*BSZ) };
  ushort_t* bB[2]  = { (ushort_t*)(bands + BSZ),     (ushort_t*)(bands + 3*BSZ) };
  ushort_t* WihB   = (ushort_t*)(ws + 201326592);      //   4,194,304
  uchar_t*  Wq8    = (uchar_t*) (ws + 205520896);      //   1,048,576 fp8 Whh
  ushort_t* WlinB  = (ushort_t*)(ws + 206569472);      //      32,768
  float*    bsum   = (float*)   (ws + 206602240);      //      16,384
  uchar_t*  hstate = (uchar_t*) (ws + 206618624);      //      65,536 fp8
  float*    cstate = (float*)   (ws + 206684160);      //     262,144
  float*    logz   = (float*)   (ws + 206946304);      //         512
  float*    partial= (float*)   (ws + 206946816);      //         512
  float*    logits = (float*)   (ws + 134217728);      // aliases bands (dead by then)

  // weight conversions
  k_cvt_bf16<<<dim3(8192),dim3(256),0,stream>>>(Wih,  WihB,  2*2*1024*512);
  k_cvt_fp8 <<<dim3(4096),dim3(256),0,stream>>>(Whh,  Wq8,   2*2*1024*256);
  k_cvt_bf16<<<dim3(64),  dim3(256),0,stream>>>(Wlin, WlinB, 32*512);
  k_biassum <<<dim3(16),  dim3(256),0,stream>>>(bih, bhh, bsum, 2*2*1024);

  // embedding
  k_embed<<<dim3(MROWS),dim3(64),0,stream>>>(src, emb, xA);

  for(int l=0;l<2;++l){
    const ushort_t* xin = l ? xB : xA;
    ushort_t*      xo   = l ? xA : xB;
    hipMemsetAsync(hstate, 0, 65536 + 262144, stream);
    const uchar_t*  WqL   = Wq8  + (size_t)l*2*1024*HIDDEN;
    const ushort_t* WihL  = WihB + (size_t)l*2*1024*DMODEL;
    const float*    bsumL = bsum + l*2*1024;
    // prologue: chunk 0 bands (full chip)
    k_gemm_pre<<<dim3(16, CHUNK*BATCH/64),dim3(256),0,stream>>>(
        xin, WihL, bsumL, bF[0]);
    k_gemm_pre<<<dim3(16, CHUNK*BATCH/64),dim3(256),0,stream>>>(
        xin + (size_t)(S_LEN-CHUNK)*BATCH*DMODEL, WihL + (size_t)1024*DMODEL,
        bsumL + 1024, bB[0]);
    for(int c=0;c<NCH;++c){
      int par = c & 1;
      int t0 = c*CHUNK;
      int ngem = (c+1 < NCH) ? 1 : 0;
      k_fused<<<dim3(256),dim3(512),0,stream>>>(
          bF[par], bB[par], WqL, hstate, cstate, xo, t0,
          xin, WihL, bsumL, bF[par^1], bB[par^1], t0 + CHUNK, ngem);
    }
  }

  k_logits<<<dim3(MROWS/16),dim3(128),0,stream>>>(xA, WlinB, blin, logits);
  k_crf   <<<dim3(BATCH),dim3(64),0,stream>>>(logits, trans, logz);
  k_gold  <<<dim3(BATCH),dim3(256),0,stream>>>(logits, tgt, trans, logz, partial);
  k_final <<<dim3(1),dim3(128),0,stream>>>(partial, out);
}